// Round 3
// baseline (10202.631 us; speedup 1.0000x reference)
//
#include <hip/hip_runtime.h>

#define Bdim 64
#define Tdim 512
#define Fdim 512
#define Hdim 1024
#define NKB  48          // K-blocks of 32: 16 for x (K=512) + 32 for h (K=1024)
#define NXKB 16
#define NHKB 32
#define NWG  128
#define NTHR 256

typedef __attribute__((ext_vector_type(8))) _Float16            f16x8;
typedef __attribute__((ext_vector_type(4))) float               f32x4;
typedef __attribute__((ext_vector_type(2))) unsigned long long  u64x2;

#define MFMA(a, b, c) __builtin_amdgcn_mfma_f32_16x16x32_f16((a), (b), (c), 0, 0, 0)

// ---- workspace layout (bytes) ----
#define WP_ELEMS  (256*48*64*8)                      // fp16 fragment-linear weights
#define BIAS_OFF  ((size_t)WP_ELEMS * 2)
#define HBUF_OFF  (BIAS_OFF + 4096 * 4)              // fp16[2][64][1024] double buffer
#define FLAG_OFF  (HBUF_OFF + (size_t)2 * Bdim * Hdim * 2)  // uint flags[NWG]

__device__ __forceinline__ float sigmoidf_(float v) {
    return 1.0f / (1.0f + __expf(-v));
}
__device__ __forceinline__ float tanhf_(float v) {
    return 1.0f - 2.0f / (1.0f + __expf(2.0f * v));
}

// Packed col Np = wg*32 + gate*8 + c  <->  orig col n = gate*1024 + wg*8 + c.
// Wp8[(tile*48 + kb)*64 + lane] = Wfull[kb*32 + (lane>>4)*8 + j][orig(tile*16 + (lane&15))]
__global__ void pack_w_kernel(const float* __restrict__ Wi, const float* __restrict__ Wh,
                              _Float16* __restrict__ Wp)
{
    int d = blockIdx.x * blockDim.x + threadIdx.x;   // 0 .. 786431
    int tn   = d / 3072;
    int r    = d % 3072;
    int kb   = r / 64;
    int lane = r % 64;
    int kg = lane >> 4, lm = lane & 15;
    int Np = tn * 16 + lm;
    int g    = Np >> 5;
    int lc   = Np & 31;
    int gate = lc >> 3, c = lc & 7;
    int n  = gate * Hdim + g * 8 + c;
    int k0 = kb * 32 + kg * 8;
    f16x8 v;
#pragma unroll
    for (int j = 0; j < 8; ++j) {
        int k = k0 + j;
        float w = (k < Fdim) ? Wi[(long)k * 4096 + n] : Wh[(long)(k - Fdim) * 4096 + n];
        v[j] = (_Float16)w;
    }
    ((f16x8*)Wp)[d] = v;
}

__global__ void pack_misc_kernel(const float* __restrict__ bh, const float* __restrict__ h0,
                                 float* __restrict__ bias_p, _Float16* __restrict__ hbuf,
                                 unsigned int* __restrict__ flags)
{
    int t = blockIdx.x * blockDim.x + threadIdx.x;
    if (t < NWG) flags[t] = 0u;                       // re-armed every launch (graph replay safe)
    if (t < 4096) {
        int g = t >> 5, lc = t & 31;
        int gate = lc >> 3, c = lc & 7;
        bias_p[t] = bh[gate * Hdim + g * 8 + c];
    }
    if (t < Bdim * Hdim) {
        hbuf[t] = (_Float16)h0[t];                    // buffer 0 = h at t=0
    }
}

__global__ __launch_bounds__(NTHR, 1)
void lstm_kernel(const float* __restrict__ x, const float* __restrict__ c0,
                 const f16x8* __restrict__ Wp8, const float* __restrict__ bias_p,
                 unsigned int* __restrict__ hbuf, unsigned int* __restrict__ flags,
                 float* __restrict__ out)
{
    __shared__ f16x8 wlds[2 * NKB * 64];              // 96 KiB weight slice
    __shared__ float zlds[Bdim][33];                  // 8.25 KiB

    const int wg   = blockIdx.x;
    const int tid  = threadIdx.x;
    const int wave = tid >> 6;
    const int lane = tid & 63;
    const int kg = lane >> 4;
    const int lm = lane & 15;

    // ---- stage the WG's weight slice into LDS once ----
    {
        const f16x8* src = Wp8 + (size_t)wg * 2 * NKB * 64;
        for (int e = tid; e < 2 * NKB * 64; e += NTHR) wlds[e] = src[e];
    }

    const float bias0 = bias_p[wg * 32 + lm];
    const float bias1 = bias_p[wg * 32 + 16 + lm];

    // gate-phase ownership: thread owns h cols (jl0, jl0+1) of batch row b0
    const int p0 = tid * 2;
    const int b0 = p0 >> 3, jl0 = p0 & 7;             // jl0 even
    const int jc = wg * 8;
    float cc0 = c0[b0 * Hdim + jc + jl0];
    float cc1 = c0[b0 * Hdim + jc + jl0 + 1];

    const int arow = wave * 16 + lm;                  // MFMA A-operand row (batch)
    const float* __restrict__ xrow = x + (size_t)arow * Tdim * Fdim + kg * 8;

    // ---- prefetch x fragments for t=0 (nontemporal: read-once data) ----
    f16x8 xf[NXKB];
#pragma unroll
    for (int kb = 0; kb < NXKB; ++kb) {
        const f32x4* ap = (const f32x4*)(xrow + kb * 32);
        f32x4 lo = __builtin_nontemporal_load(ap);
        f32x4 hi = __builtin_nontemporal_load(ap + 1);
        f16x8 a;
#pragma unroll
        for (int j = 0; j < 4; ++j) { a[j] = (_Float16)lo[j]; a[4 + j] = (_Float16)hi[j]; }
        xf[kb] = a;
    }

    // h A-fragment addressing in u64 units (8 halves = 16B = 2 u64 per fragment)
    const unsigned long long* __restrict__ hbase64 =
        (const unsigned long long*)hbuf + (size_t)arow * (Hdim / 4) + kg * 2;

    __syncthreads();                                  // wlds ready

    for (int t = 0; t < Tdim; ++t) {
        const int cur = t & 1;
        const unsigned long long* hb64 = hbase64 + (size_t)cur * (Bdim * Hdim / 4);

        f32x4 acc0a = {bias0, bias0, bias0, bias0};
        f32x4 acc1a = {bias1, bias1, bias1, bias1};
        f32x4 acc0b = {0.f, 0.f, 0.f, 0.f};
        f32x4 acc1b = {0.f, 0.f, 0.f, 0.f};

        // ---- x part of K (from registers) — runs while h(t) propagates ----
#pragma unroll 4
        for (int kb = 0; kb < NXKB; ++kb) {
            f16x8 a   = xf[kb];
            f16x8 bf0 = wlds[kb * 64 + lane];
            f16x8 bf1 = wlds[NKB * 64 + kb * 64 + lane];
            if (kb & 1) { acc0b = MFMA(a, bf0, acc0b); acc1b = MFMA(a, bf1, acc1b); }
            else        { acc0a = MFMA(a, bf0, acc0a); acc1a = MFMA(a, bf1, acc1a); }
        }

        // ---- wait until all WGs have published h(t) (t=0: ready from pack_misc) ----
        if (t) {
            const unsigned int gen = (unsigned int)t;
            while (true) {
                unsigned int f0 = __hip_atomic_load(flags + lane,      __ATOMIC_RELAXED, __HIP_MEMORY_SCOPE_AGENT);
                unsigned int f1 = __hip_atomic_load(flags + 64 + lane, __ATOMIC_RELAXED, __HIP_MEMORY_SCOPE_AGENT);
                if (__all(f0 >= gen && f1 >= gen)) break;
                __builtin_amdgcn_s_sleep(1);
            }
            asm volatile("" ::: "memory");            // no load motion across the poll
        }

        // ---- h part of K: issue ALL loads first (deep MALL pipeline), then MFMA ----
        f16x8 hfrag[NHKB];
#pragma unroll
        for (int kb = 0; kb < NHKB; ++kb) {
            const unsigned long long* hp = hb64 + kb * 8;
            u64x2 r;
            r.x = __hip_atomic_load(hp,     __ATOMIC_RELAXED, __HIP_MEMORY_SCOPE_AGENT);
            r.y = __hip_atomic_load(hp + 1, __ATOMIC_RELAXED, __HIP_MEMORY_SCOPE_AGENT);
            hfrag[kb] = __builtin_bit_cast(f16x8, r);
        }
#pragma unroll
        for (int kb = 0; kb < NHKB; ++kb) {
            f16x8 a   = hfrag[kb];
            f16x8 bf0 = wlds[(NXKB + kb) * 64 + lane];
            f16x8 bf1 = wlds[NKB * 64 + (NXKB + kb) * 64 + lane];
            if (kb & 1) { acc0b = MFMA(a, bf0, acc0b); acc1b = MFMA(a, bf1, acc1b); }
            else        { acc0a = MFMA(a, bf0, acc0a); acc1a = MFMA(a, bf1, acc1a); }
        }
        f32x4 z0 = acc0a + acc0b;
        f32x4 z1 = acc1a + acc1b;

        // D layout: row = (lane>>4)*4 + r, col = lane&15
        {
            int rbase = wave * 16 + kg * 4;
#pragma unroll
            for (int r = 0; r < 4; ++r) {
                zlds[rbase + r][lm]      = z0[r];
                zlds[rbase + r][16 + lm] = z1[r];
            }
        }
        __syncthreads();

        // ---- gates (local cols: i 0..7, f 8..15, g 16..23, o 24..31) ----
        float zi0 = zlds[b0][jl0],      zi1 = zlds[b0][jl0 + 1];
        float zf0 = zlds[b0][8 + jl0],  zf1 = zlds[b0][8 + jl0 + 1];
        float zg0 = zlds[b0][16 + jl0], zg1 = zlds[b0][16 + jl0 + 1];
        float zo0 = zlds[b0][24 + jl0], zo1 = zlds[b0][24 + jl0 + 1];

        float i0 = sigmoidf_(zi0), f0 = sigmoidf_(zf0);
        float g0 = tanhf_(zg0),    o0 = sigmoidf_(zo0);
        cc0 = f0 * cc0 + i0 * g0;
        float hv0 = o0 * tanhf_(cc0);

        float i1 = sigmoidf_(zi1), f1 = sigmoidf_(zf1);
        float g1 = tanhf_(zg1),    o1 = sigmoidf_(zo1);
        cc1 = f1 * cc1 + i1 * g1;
        float hv1 = o1 * tanhf_(cc1);

        // ---- publish h(t+1): packed 2x fp16 agent-scope store (to MALL) ----
        {
            union { _Float16 h[2]; unsigned int u; } pk;
            pk.h[0] = (_Float16)hv0; pk.h[1] = (_Float16)hv1;
            unsigned int hidx = (unsigned int)((b0 * Hdim + jc + jl0) >> 1);
            __hip_atomic_store(hbuf + (size_t)(cur ^ 1) * (Bdim * Hdim / 2) + hidx,
                               pk.u, __ATOMIC_RELAXED, __HIP_MEMORY_SCOPE_AGENT);
        }
        __builtin_amdgcn_s_waitcnt(0);                // this wave's h stores are at the MALL
        __syncthreads();                              // all 4 waves drained (also fences zlds reuse)
        if (tid == 0)
            __hip_atomic_store(flags + wg, (unsigned int)(t + 1),
                               __ATOMIC_RELEASE, __HIP_MEMORY_SCOPE_AGENT);

        // ---- off-critical-path work: out store + x prefetch for t+1 ----
        {
            union { float f[2]; unsigned long long u; } ov;
            ov.f[0] = hv0; ov.f[1] = hv1;
            __builtin_nontemporal_store(ov.u,
                (unsigned long long*)(out + ((size_t)b0 * Tdim + t) * Hdim + jc + jl0));
        }
        {
            int tn = (t + 1 < Tdim) ? (t + 1) : t;
            const float* xp = xrow + (size_t)tn * Fdim;
#pragma unroll
            for (int kb = 0; kb < NXKB; ++kb) {
                const f32x4* ap = (const f32x4*)(xp + kb * 32);
                f32x4 lo = __builtin_nontemporal_load(ap);
                f32x4 hi = __builtin_nontemporal_load(ap + 1);
                f16x8 a;
#pragma unroll
                for (int j = 0; j < 4; ++j) { a[j] = (_Float16)lo[j]; a[4 + j] = (_Float16)hi[j]; }
                xf[kb] = a;
            }
        }
    }
}

extern "C" void kernel_launch(void* const* d_in, const int* in_sizes, int n_in,
                              void* d_out, int out_size, void* d_ws, size_t ws_size,
                              hipStream_t stream)
{
    const float* x  = (const float*)d_in[0];
    const float* c0 = (const float*)d_in[1];
    const float* h0 = (const float*)d_in[2];
    const float* Wi = (const float*)d_in[3];
    const float* Wh = (const float*)d_in[4];
    const float* bh = (const float*)d_in[5];
    float* out = (float*)d_out;

    char* ws = (char*)d_ws;
    _Float16*     Wp     = (_Float16*)(ws);
    float*        bias_p = (float*)(ws + BIAS_OFF);
    _Float16*     hbufh  = (_Float16*)(ws + HBUF_OFF);
    unsigned int* hbuf   = (unsigned int*)(ws + HBUF_OFF);
    unsigned int* flags  = (unsigned int*)(ws + FLAG_OFF);

    hipLaunchKernelGGL(pack_w_kernel,    dim3(3072), dim3(256), 0, stream, Wi, Wh, Wp);
    hipLaunchKernelGGL(pack_misc_kernel, dim3(256),  dim3(256), 0, stream, bh, h0, bias_p, hbufh, flags);
    hipLaunchKernelGGL(lstm_kernel, dim3(NWG), dim3(NTHR), 0, stream,
                       x, c0, (const f16x8*)Wp, bias_p, hbuf, flags, out);
}

// Round 4
// 9924.861 us; speedup vs baseline: 1.0280x; 1.0280x over previous
//
#include <hip/hip_runtime.h>

#define Bdim 64
#define Tdim 512
#define Fdim 512
#define Hdim 1024
#define NKB  48          // K-blocks of 32: 16 for x (K=512) + 32 for h (K=1024)
#define NXKB 16
#define NHKB 32
#define NWG  128
#define NTHR 256

typedef __attribute__((ext_vector_type(8))) _Float16            f16x8;
typedef __attribute__((ext_vector_type(4))) float               f32x4;

#define MFMA(a, b, c) __builtin_amdgcn_mfma_f32_16x16x32_f16((a), (b), (c), 0, 0, 0)

// ---- workspace layout (bytes) ----
#define WP_ELEMS  (256*48*64*8)                      // fp16 fragment-linear weights
#define BIAS_OFF  ((size_t)WP_ELEMS * 2)
#define HBUF_OFF  (BIAS_OFF + 4096 * 4)              // fp16[2][64][1024] double buffer
#define FLAG_OFF  (HBUF_OFF + (size_t)2 * Bdim * Hdim * 2)  // uint flags[NWG]

__device__ __forceinline__ float sigmoidf_(float v) {
    return 1.0f / (1.0f + __expf(-v));
}
__device__ __forceinline__ float tanhf_(float v) {
    return 1.0f - 2.0f / (1.0f + __expf(2.0f * v));
}

// Packed col Np = wg*32 + gate*8 + c  <->  orig col n = gate*1024 + wg*8 + c.
// Wp8[(tile*48 + kb)*64 + lane] = Wfull[kb*32 + (lane>>4)*8 + j][orig(tile*16 + (lane&15))]
__global__ void pack_w_kernel(const float* __restrict__ Wi, const float* __restrict__ Wh,
                              _Float16* __restrict__ Wp)
{
    int d = blockIdx.x * blockDim.x + threadIdx.x;   // 0 .. 786431
    int tn   = d / 3072;
    int r    = d % 3072;
    int kb   = r / 64;
    int lane = r % 64;
    int kg = lane >> 4, lm = lane & 15;
    int Np = tn * 16 + lm;
    int g    = Np >> 5;
    int lc   = Np & 31;
    int gate = lc >> 3, c = lc & 7;
    int n  = gate * Hdim + g * 8 + c;
    int k0 = kb * 32 + kg * 8;
    f16x8 v;
#pragma unroll
    for (int j = 0; j < 8; ++j) {
        int k = k0 + j;
        float w = (k < Fdim) ? Wi[(long)k * 4096 + n] : Wh[(long)(k - Fdim) * 4096 + n];
        v[j] = (_Float16)w;
    }
    ((f16x8*)Wp)[d] = v;
}

__global__ void pack_misc_kernel(const float* __restrict__ bh, const float* __restrict__ h0,
                                 float* __restrict__ bias_p, _Float16* __restrict__ hbuf,
                                 unsigned int* __restrict__ flags)
{
    int t = blockIdx.x * blockDim.x + threadIdx.x;
    if (t < NWG) flags[t] = 0u;                       // re-armed every launch (graph replay safe)
    if (t < 4096) {
        int g = t >> 5, lc = t & 31;
        int gate = lc >> 3, c = lc & 7;
        bias_p[t] = bh[gate * Hdim + g * 8 + c];
    }
    if (t < Bdim * Hdim) {
        hbuf[t] = (_Float16)h0[t];                    // buffer 0 = h at t=0
    }
}

__global__ __launch_bounds__(NTHR, 1)
void lstm_kernel(const float* __restrict__ x, const float* __restrict__ c0,
                 const f16x8* __restrict__ Wp8, const float* __restrict__ bias_p,
                 unsigned int* __restrict__ hbuf, unsigned int* __restrict__ flags,
                 float* __restrict__ out)
{
    __shared__ f16x8 wlds[2 * NKB * 64];              // 96 KiB weight slice
    __shared__ float zlds[Bdim][33];                  // 8.25 KiB

    // XCD-grouped logical wg: physical blocks p=8k..8k+7 round-robin XCDs, so
    // logical wgs 16x..16x+15 all live on XCD x -> the 4 WGs sharing each
    // 128B out-line (wg 4k..4k+3) share an L2 (partial writes merge in L2).
    const int wg   = (blockIdx.x & 7) * 16 + (blockIdx.x >> 3);
    const int tid  = threadIdx.x;
    const int wave = tid >> 6;
    const int lane = tid & 63;
    const int kg = lane >> 4;
    const int lm = lane & 15;

    // ---- stage the WG's weight slice into LDS once ----
    {
        const f16x8* src = Wp8 + (size_t)wg * 2 * NKB * 64;
        for (int e = tid; e < 2 * NKB * 64; e += NTHR) wlds[e] = src[e];
    }

    const float bias0 = bias_p[wg * 32 + lm];
    const float bias1 = bias_p[wg * 32 + 16 + lm];

    // gate-phase ownership: thread owns h cols (jl0, jl0+1) of batch row b0
    const int p0 = tid * 2;
    const int b0 = p0 >> 3, jl0 = p0 & 7;             // jl0 even
    const int jc = wg * 8;
    float cc0 = c0[b0 * Hdim + jc + jl0];
    float cc1 = c0[b0 * Hdim + jc + jl0 + 1];

    const int arow = wave * 16 + lm;                  // MFMA A-operand row (batch)
    const float* __restrict__ xrow = x + (size_t)arow * Tdim * Fdim + kg * 8;

    // ---- prefetch x fragments for t=0 ----
    f16x8 xf[NXKB];
#pragma unroll
    for (int kb = 0; kb < NXKB; ++kb) {
        const float* ap = xrow + kb * 32;
        f16x8 a;
#pragma unroll
        for (int j = 0; j < 8; ++j) a[j] = (_Float16)ap[j];
        xf[kb] = a;
    }

    const _Float16* __restrict__ hbufh = (const _Float16*)hbuf;

    __syncthreads();                                  // wlds ready

    for (int t = 0; t < Tdim; ++t) {
        const int cur = t & 1;
        // per-lane h row base: fragment kb -> hrow8[kb*4 + kg]
        const f16x8* __restrict__ hrow8 =
            (const f16x8*)(hbufh + (size_t)cur * (Bdim * Hdim) + (size_t)arow * Hdim);

        f32x4 acc0a = {bias0, bias0, bias0, bias0};
        f32x4 acc1a = {bias1, bias1, bias1, bias1};
        f32x4 acc0b = {0.f, 0.f, 0.f, 0.f};
        f32x4 acc1b = {0.f, 0.f, 0.f, 0.f};

        // ---- x part of K (from registers) — overlaps h(t) propagation ----
#pragma unroll 4
        for (int kb = 0; kb < NXKB; ++kb) {
            f16x8 a   = xf[kb];
            f16x8 bf0 = wlds[kb * 64 + lane];
            f16x8 bf1 = wlds[NKB * 64 + kb * 64 + lane];
            if (kb & 1) { acc0b = MFMA(a, bf0, acc0b); acc1b = MFMA(a, bf1, acc1b); }
            else        { acc0a = MFMA(a, bf0, acc0a); acc1a = MFMA(a, bf1, acc1a); }
        }

        // ---- wave 0 polls until all WGs published h(t); others wait at barrier ----
        if (t && wave == 0) {
            const unsigned int gen = (unsigned int)t;
            while (true) {
                unsigned int f0 = __hip_atomic_load(flags + lane,      __ATOMIC_RELAXED, __HIP_MEMORY_SCOPE_AGENT);
                unsigned int f1 = __hip_atomic_load(flags + 64 + lane, __ATOMIC_RELAXED, __HIP_MEMORY_SCOPE_AGENT);
                if (__all(f0 >= gen && f1 >= gen)) break;
                __builtin_amdgcn_s_sleep(2);
            }
        }
        __syncthreads();
        // Acquire at agent scope: invalidate L1+L2 so plain h loads see the
        // write-through (MALL) values published by remote XCDs.
        __builtin_amdgcn_fence(__ATOMIC_ACQUIRE, "agent");

        // ---- h part of K: PLAIN vector loads (compiler software-pipelines) ----
#pragma unroll 8
        for (int kb = 0; kb < NHKB; ++kb) {
            f16x8 a   = hrow8[kb * 4 + kg];
            f16x8 bf0 = wlds[(NXKB + kb) * 64 + lane];
            f16x8 bf1 = wlds[NKB * 64 + (NXKB + kb) * 64 + lane];
            if (kb & 1) { acc0b = MFMA(a, bf0, acc0b); acc1b = MFMA(a, bf1, acc1b); }
            else        { acc0a = MFMA(a, bf0, acc0a); acc1a = MFMA(a, bf1, acc1a); }
        }
        f32x4 z0 = acc0a + acc0b;
        f32x4 z1 = acc1a + acc1b;

        // D layout: row = (lane>>4)*4 + r, col = lane&15
        {
            int rbase = wave * 16 + kg * 4;
#pragma unroll
            for (int r = 0; r < 4; ++r) {
                zlds[rbase + r][lm]      = z0[r];
                zlds[rbase + r][16 + lm] = z1[r];
            }
        }
        __syncthreads();

        // ---- gates (local cols: i 0..7, f 8..15, g 16..23, o 24..31) ----
        float zi0 = zlds[b0][jl0],      zi1 = zlds[b0][jl0 + 1];
        float zf0 = zlds[b0][8 + jl0],  zf1 = zlds[b0][8 + jl0 + 1];
        float zg0 = zlds[b0][16 + jl0], zg1 = zlds[b0][16 + jl0 + 1];
        float zo0 = zlds[b0][24 + jl0], zo1 = zlds[b0][24 + jl0 + 1];

        float i0 = sigmoidf_(zi0), f0 = sigmoidf_(zf0);
        float g0 = tanhf_(zg0),    o0 = sigmoidf_(zo0);
        cc0 = f0 * cc0 + i0 * g0;
        float hv0 = o0 * tanhf_(cc0);

        float i1 = sigmoidf_(zi1), f1 = sigmoidf_(zf1);
        float g1 = tanhf_(zg1),    o1 = sigmoidf_(zo1);
        cc1 = f1 * cc1 + i1 * g1;
        float hv1 = o1 * tanhf_(cc1);

        // ---- publish h(t+1): packed 2x fp16 agent-scope store (write-through to MALL) ----
        {
            union { _Float16 h[2]; unsigned int u; } pk;
            pk.h[0] = (_Float16)hv0; pk.h[1] = (_Float16)hv1;
            unsigned int hidx = (unsigned int)((b0 * Hdim + jc + jl0) >> 1);
            __hip_atomic_store(hbuf + (size_t)(cur ^ 1) * (Bdim * Hdim / 2) + hidx,
                               pk.u, __ATOMIC_RELAXED, __HIP_MEMORY_SCOPE_AGENT);
        }
        __builtin_amdgcn_s_waitcnt(0);                // this wave's h store is at the MALL
        __syncthreads();                              // all 4 waves drained
        if (tid == 0)
            __hip_atomic_store(flags + wg, (unsigned int)(t + 1),
                               __ATOMIC_RELEASE, __HIP_MEMORY_SCOPE_AGENT);

        // ---- off-critical-path: out store (plain, line-merged in own XCD L2) ----
        {
            float2 ov; ov.x = hv0; ov.y = hv1;
            *(float2*)(out + ((size_t)b0 * Tdim + t) * Hdim + jc + jl0) = ov;
        }
        // ---- x prefetch for t+1 (plain cached loads) ----
        {
            int tn = (t + 1 < Tdim) ? (t + 1) : t;
            const float* xp = xrow + (size_t)tn * Fdim;
#pragma unroll
            for (int kb = 0; kb < NXKB; ++kb) {
                const float* ap = xp + kb * 32;
                f16x8 a;
#pragma unroll
                for (int j = 0; j < 8; ++j) a[j] = (_Float16)ap[j];
                xf[kb] = a;
            }
        }
    }
}

extern "C" void kernel_launch(void* const* d_in, const int* in_sizes, int n_in,
                              void* d_out, int out_size, void* d_ws, size_t ws_size,
                              hipStream_t stream)
{
    const float* x  = (const float*)d_in[0];
    const float* c0 = (const float*)d_in[1];
    const float* h0 = (const float*)d_in[2];
    const float* Wi = (const float*)d_in[3];
    const float* Wh = (const float*)d_in[4];
    const float* bh = (const float*)d_in[5];
    float* out = (float*)d_out;

    char* ws = (char*)d_ws;
    _Float16*     Wp     = (_Float16*)(ws);
    float*        bias_p = (float*)(ws + BIAS_OFF);
    _Float16*     hbufh  = (_Float16*)(ws + HBUF_OFF);
    unsigned int* hbuf   = (unsigned int*)(ws + HBUF_OFF);
    unsigned int* flags  = (unsigned int*)(ws + FLAG_OFF);

    hipLaunchKernelGGL(pack_w_kernel,    dim3(3072), dim3(256), 0, stream, Wi, Wh, Wp);
    hipLaunchKernelGGL(pack_misc_kernel, dim3(256),  dim3(256), 0, stream, bh, h0, bias_p, hbufh, flags);
    hipLaunchKernelGGL(lstm_kernel, dim3(NWG), dim3(NTHR), 0, stream,
                       x, c0, (const f16x8*)Wp, bias_p, hbuf, flags, out);
}

// Round 5
// 4960.110 us; speedup vs baseline: 2.0569x; 2.0009x over previous
//
#include <hip/hip_runtime.h>

#define Bdim 64
#define Tdim 512
#define Fdim 512
#define Hdim 1024
#define NKB  48          // K-blocks of 32: 16 for x (K=512) + 32 for h (K=1024)
#define NXKB 16
#define NHKB 32
#define NWG  128
#define NTHR 256

typedef __attribute__((ext_vector_type(8))) _Float16            f16x8;
typedef __attribute__((ext_vector_type(4))) float               f32x4;

#define MFMA(a, b, c) __builtin_amdgcn_mfma_f32_16x16x32_f16((a), (b), (c), 0, 0, 0)

// ---- workspace layout (bytes) ----
// Wp    : fp16 fragment-linear weights, 12.6 MB
// bias_p: fp32[4096]
// hbuf  : fp16[2][128 wg][64 b][8 c]  (2 x 128 KiB, compact per-WG blocks)
// flags : uint[NWG] padded to one 128B line each (stride 32 uints)
#define WP_ELEMS  (256*48*64*8)
#define BIAS_OFF  ((size_t)WP_ELEMS * 2)
#define HBUF_OFF  (BIAS_OFF + 4096 * 4)
#define HBUF_HALF 65536                              // halves per buffer (64*1024)
#define FLAG_OFF  (HBUF_OFF + (size_t)2 * HBUF_HALF * 2)
#define FLAG_STRIDE 32                               // uints (128 B) per flag

__device__ __forceinline__ float sigmoidf_(float v) {
    return 1.0f / (1.0f + __expf(-v));
}
__device__ __forceinline__ float tanhf_(float v) {
    return 1.0f - 2.0f / (1.0f + __expf(2.0f * v));
}

// Device-coherent (L1+L2 bypass) 16B load: data written via agent-scope
// write-through stores lives at the MALL; sc0 sc1 reads it fresh.
__device__ __forceinline__ f16x8 uload16(const void* p) {
    f16x8 r;
    asm volatile("global_load_dwordx4 %0, %1, off sc0 sc1"
                 : "=v"(r) : "v"(p) : "memory");
    return r;
}

// Packed col Np = wg*32 + gate*8 + c  <->  orig col n = gate*1024 + wg*8 + c.
// Wp8[(tile*48 + kb)*64 + lane] = Wfull[kb*32 + (lane>>4)*8 + j][orig(tile*16 + (lane&15))]
__global__ void pack_w_kernel(const float* __restrict__ Wi, const float* __restrict__ Wh,
                              _Float16* __restrict__ Wp)
{
    int d = blockIdx.x * blockDim.x + threadIdx.x;   // 0 .. 786431
    int tn   = d / 3072;
    int r    = d % 3072;
    int kb   = r / 64;
    int lane = r % 64;
    int kg = lane >> 4, lm = lane & 15;
    int Np = tn * 16 + lm;
    int g    = Np >> 5;
    int lc   = Np & 31;
    int gate = lc >> 3, c = lc & 7;
    int n  = gate * Hdim + g * 8 + c;
    int k0 = kb * 32 + kg * 8;
    f16x8 v;
#pragma unroll
    for (int j = 0; j < 8; ++j) {
        int k = k0 + j;
        float w = (k < Fdim) ? Wi[(long)k * 4096 + n] : Wh[(long)(k - Fdim) * 4096 + n];
        v[j] = (_Float16)w;
    }
    ((f16x8*)Wp)[d] = v;
}

__global__ void pack_misc_kernel(const float* __restrict__ bh, const float* __restrict__ h0,
                                 float* __restrict__ bias_p, _Float16* __restrict__ hbuf,
                                 unsigned int* __restrict__ flags)
{
    int t = blockIdx.x * blockDim.x + threadIdx.x;   // 0 .. 65535
    if (t < NWG) flags[t * FLAG_STRIDE] = 0u;        // re-armed every launch
    if (t < 4096) {
        int g = t >> 5, lc = t & 31;
        int gate = lc >> 3, c = lc & 7;
        bias_p[t] = bh[gate * Hdim + g * 8 + c];
    }
    {   // hbuf buffer 0 = h at t=0, compact layout [wg'][b][c]
        int wgp = t >> 9;
        int b   = (t >> 3) & 63;
        int c   = t & 7;
        hbuf[t] = (_Float16)h0[b * Hdim + wgp * 8 + c];
    }
}

__global__ __launch_bounds__(NTHR, 1)
void lstm_kernel(const float* __restrict__ x, const float* __restrict__ c0,
                 const f16x8* __restrict__ Wp8, const float* __restrict__ bias_p,
                 _Float16* __restrict__ hbuf, unsigned int* __restrict__ flags,
                 float* __restrict__ out)
{
    __shared__ f16x8 wlds[2 * NKB * 64];              // 96 KiB weight slice
    __shared__ float zlds[Bdim][33];                  // 8.25 KiB

    // XCD-grouped logical wg (neutral-to-positive; keeps out-line sharers together)
    const int wg   = (blockIdx.x & 7) * 16 + (blockIdx.x >> 3);
    const int tid  = threadIdx.x;
    const int wave = tid >> 6;
    const int lane = tid & 63;
    const int kg = lane >> 4;
    const int lm = lane & 15;

    // ---- stage the WG's weight slice into LDS once ----
    {
        const f16x8* src = Wp8 + (size_t)wg * 2 * NKB * 64;
        for (int e = tid; e < 2 * NKB * 64; e += NTHR) wlds[e] = src[e];
    }

    const float bias0 = bias_p[wg * 32 + lm];
    const float bias1 = bias_p[wg * 32 + 16 + lm];

    // gate-phase ownership: wave 0, lane b owns all 8 h cols of batch row b
    float cc[8];
    if (wave == 0) {
#pragma unroll
        for (int c = 0; c < 8; ++c) cc[c] = c0[lane * Hdim + wg * 8 + c];
    }

    const int arow = wave * 16 + lm;                  // MFMA A-operand row (batch)
    const float* __restrict__ xrow = x + (size_t)arow * Tdim * Fdim + kg * 8;

    // ---- prefetch x fragments for t=0 ----
    f16x8 xf[NXKB];
#pragma unroll
    for (int kb = 0; kb < NXKB; ++kb) {
        const float* ap = xrow + kb * 32;
        f16x8 a;
#pragma unroll
        for (int j = 0; j < 8; ++j) a[j] = (_Float16)ap[j];
        xf[kb] = a;
    }

    // per-lane h' read base (bytes): frag kb at +kb*4096
    const char* __restrict__ hrdbase =
        (const char*)hbuf + (size_t)kg * 1024 + (size_t)arow * 16;

    __syncthreads();                                  // wlds ready

    for (int t = 0; t < Tdim; ++t) {
        const int cur = t & 1;

        f32x4 acc0a = {bias0, bias0, bias0, bias0};
        f32x4 acc1a = {bias1, bias1, bias1, bias1};
        f32x4 acc0b = {0.f, 0.f, 0.f, 0.f};
        f32x4 acc1b = {0.f, 0.f, 0.f, 0.f};

        // ---- x part of K (from registers) — overlaps h(t) propagation ----
#pragma unroll 4
        for (int kb = 0; kb < NXKB; ++kb) {
            f16x8 a   = xf[kb];
            f16x8 bf0 = wlds[kb * 64 + lane];
            f16x8 bf1 = wlds[NKB * 64 + kb * 64 + lane];
            if (kb & 1) { acc0b = MFMA(a, bf0, acc0b); acc1b = MFMA(a, bf1, acc1b); }
            else        { acc0a = MFMA(a, bf0, acc0a); acc1a = MFMA(a, bf1, acc1a); }
        }

        // ---- wave 0 polls until all WGs published h(t); others wait at barrier ----
        if (t && wave == 0) {
            const unsigned int gen = (unsigned int)t;
            while (true) {
                unsigned int f0 = __hip_atomic_load(flags + (size_t)lane * FLAG_STRIDE,
                                                    __ATOMIC_RELAXED, __HIP_MEMORY_SCOPE_AGENT);
                unsigned int f1 = __hip_atomic_load(flags + (size_t)(64 + lane) * FLAG_STRIDE,
                                                    __ATOMIC_RELAXED, __HIP_MEMORY_SCOPE_AGENT);
                if (__all(f0 >= gen && f1 >= gen)) break;
                __builtin_amdgcn_s_sleep(2);
            }
        }
        __syncthreads();                              // (A) h(t) globally published

        // ---- h part of K: 32 batched device-coherent loads, ONE round trip ----
        f16x8 hfrag[NHKB];
        {
            const char* hq = hrdbase + (size_t)cur * (HBUF_HALF * 2);
#pragma unroll
            for (int kb = 0; kb < NHKB; ++kb)
                hfrag[kb] = uload16(hq + (size_t)kb * 4096);
        }
        asm volatile("s_waitcnt vmcnt(0)" ::: "memory");
        __builtin_amdgcn_sched_barrier(0);

#pragma unroll
        for (int kb = 0; kb < NHKB; ++kb) {
            f16x8 a   = hfrag[kb];
            f16x8 bf0 = wlds[(NXKB + kb) * 64 + lane];
            f16x8 bf1 = wlds[NKB * 64 + (NXKB + kb) * 64 + lane];
            if (kb & 1) { acc0b = MFMA(a, bf0, acc0b); acc1b = MFMA(a, bf1, acc1b); }
            else        { acc0a = MFMA(a, bf0, acc0a); acc1a = MFMA(a, bf1, acc1a); }
        }
        f32x4 z0 = acc0a + acc0b;
        f32x4 z1 = acc1a + acc1b;

        // D layout: row = (lane>>4)*4 + r, col = lane&15
        {
            int rbase = wave * 16 + kg * 4;
#pragma unroll
            for (int r = 0; r < 4; ++r) {
                zlds[rbase + r][lm]      = z0[r];
                zlds[rbase + r][16 + lm] = z1[r];
            }
        }
        __syncthreads();                              // (B) z ready

        if (wave == 0) {
            // ---- gates: lane b owns 8 cols (i=c, f=8+c, g=16+c, o=24+c) ----
            const int b = lane;
            float hv[8];
#pragma unroll
            for (int c = 0; c < 8; ++c) {
                float ig = sigmoidf_(zlds[b][c]);
                float fg = sigmoidf_(zlds[b][8 + c]);
                float gg = tanhf_(zlds[b][16 + c]);
                float og = sigmoidf_(zlds[b][24 + c]);
                cc[c] = fg * cc[c] + ig * gg;
                hv[c] = og * tanhf_(cc[c]);
            }
            // publish h(t+1): 16B contiguous per lane -> WG block fully covered
            union { _Float16 h[8]; unsigned long long u[2]; } pk;
#pragma unroll
            for (int c = 0; c < 8; ++c) pk.h[c] = (_Float16)hv[c];
            unsigned long long* hst = (unsigned long long*)
                (hbuf + (size_t)(cur ^ 1) * HBUF_HALF + (size_t)wg * 512 + (size_t)b * 8);
            __hip_atomic_store(hst,     pk.u[0], __ATOMIC_RELAXED, __HIP_MEMORY_SCOPE_AGENT);
            __hip_atomic_store(hst + 1, pk.u[1], __ATOMIC_RELAXED, __HIP_MEMORY_SCOPE_AGENT);
            asm volatile("s_waitcnt vmcnt(0)" ::: "memory");   // h' acked at MALL
            if (lane == 0)
                __hip_atomic_store(flags + (size_t)wg * FLAG_STRIDE, (unsigned int)(t + 1),
                                   __ATOMIC_RELAXED, __HIP_MEMORY_SCOPE_AGENT);
            // off-critical-path: out store (plain cached)
            float* op = out + ((size_t)b * Tdim + t) * Hdim + wg * 8;
            f32x4 o0 = {hv[0], hv[1], hv[2], hv[3]};
            f32x4 o1 = {hv[4], hv[5], hv[6], hv[7]};
            *(f32x4*)op       = o0;
            *(f32x4*)(op + 4) = o1;
        }

        // ---- x prefetch for t+1 (all waves; off critical path) ----
        {
            int tn = (t + 1 < Tdim) ? (t + 1) : t;
            const float* xp = xrow + (size_t)tn * Fdim;
#pragma unroll
            for (int kb = 0; kb < NXKB; ++kb) {
                const float* ap = xp + kb * 32;
                f16x8 a;
#pragma unroll
                for (int j = 0; j < 8; ++j) a[j] = (_Float16)ap[j];
                xf[kb] = a;
            }
        }
        // next iteration's barrier (A) orders: gates(t) done before zlds(t+1) writes
    }
}

extern "C" void kernel_launch(void* const* d_in, const int* in_sizes, int n_in,
                              void* d_out, int out_size, void* d_ws, size_t ws_size,
                              hipStream_t stream)
{
    const float* x  = (const float*)d_in[0];
    const float* c0 = (const float*)d_in[1];
    const float* h0 = (const float*)d_in[2];
    const float* Wi = (const float*)d_in[3];
    const float* Wh = (const float*)d_in[4];
    const float* bh = (const float*)d_in[5];
    float* out = (float*)d_out;

    char* ws = (char*)d_ws;
    _Float16*     Wp     = (_Float16*)(ws);
    float*        bias_p = (float*)(ws + BIAS_OFF);
    _Float16*     hbuf   = (_Float16*)(ws + HBUF_OFF);
    unsigned int* flags  = (unsigned int*)(ws + FLAG_OFF);

    hipLaunchKernelGGL(pack_w_kernel,    dim3(3072), dim3(256), 0, stream, Wi, Wh, Wp);
    hipLaunchKernelGGL(pack_misc_kernel, dim3(256),  dim3(256), 0, stream, bh, h0, bias_p, hbuf, flags);
    hipLaunchKernelGGL(lstm_kernel, dim3(NWG), dim3(NTHR), 0, stream,
                       x, c0, (const f16x8*)Wp, bias_p, hbuf, flags, out);
}

// Round 6
// 3889.273 us; speedup vs baseline: 2.6233x; 1.2753x over previous
//
#include <hip/hip_runtime.h>

#define Bdim 64
#define Tdim 512
#define Fdim 512
#define Hdim 1024
#define NKB  48          // K-blocks of 32: 16 for x (K=512) + 32 for h (K=1024)
#define NXKB 16
#define NHKB 32
#define NWG  128
#define NTHR 256

typedef __attribute__((ext_vector_type(8))) _Float16            f16x8;
typedef __attribute__((ext_vector_type(4))) float               f32x4;

#define MFMA(a, b, c) __builtin_amdgcn_mfma_f32_16x16x32_f16((a), (b), (c), 0, 0, 0)

// ---- workspace layout (bytes) ----
// Wp    : fp16 fragment-linear weights, 12.6 MB
// bias_p: fp32[4096]
// hbuf  : fp16[2][128 wg][64 b][8 c]  (2 x 128 KiB, compact per-WG blocks)
// flags : uint[NWG] padded to one 128B line each (stride 32 uints)
#define WP_ELEMS  (256*48*64*8)
#define BIAS_OFF  ((size_t)WP_ELEMS * 2)
#define HBUF_OFF  (BIAS_OFF + 4096 * 4)
#define HBUF_HALF 65536                              // halves per buffer (64*1024)
#define FLAG_OFF  (HBUF_OFF + (size_t)2 * HBUF_HALF * 2)
#define FLAG_STRIDE 32                               // uints (128 B) per flag

__device__ __forceinline__ float sigmoidf_(float v) {
    return 1.0f / (1.0f + __expf(-v));
}
__device__ __forceinline__ float tanhf_(float v) {
    return 1.0f - 2.0f / (1.0f + __expf(2.0f * v));
}

// Device-coherent (L1+L2 bypass) 16B load: data written via agent-scope
// write-through stores lives at the MALL; sc0 sc1 reads it fresh.
__device__ __forceinline__ f16x8 uload16(const void* p) {
    f16x8 r;
    asm volatile("global_load_dwordx4 %0, %1, off sc0 sc1"
                 : "=v"(r) : "v"(p) : "memory");
    return r;
}

// Packed col Np = wg*32 + gate*8 + c  <->  orig col n = gate*1024 + wg*8 + c.
// Wp8[(tile*48 + kb)*64 + lane] = Wfull[kb*32 + (lane>>4)*8 + j][orig(tile*16 + (lane&15))]
__global__ void pack_w_kernel(const float* __restrict__ Wi, const float* __restrict__ Wh,
                              _Float16* __restrict__ Wp)
{
    int d = blockIdx.x * blockDim.x + threadIdx.x;   // 0 .. 786431
    int tn   = d / 3072;
    int r    = d % 3072;
    int kb   = r / 64;
    int lane = r % 64;
    int kg = lane >> 4, lm = lane & 15;
    int Np = tn * 16 + lm;
    int g    = Np >> 5;
    int lc   = Np & 31;
    int gate = lc >> 3, c = lc & 7;
    int n  = gate * Hdim + g * 8 + c;
    int k0 = kb * 32 + kg * 8;
    f16x8 v;
#pragma unroll
    for (int j = 0; j < 8; ++j) {
        int k = k0 + j;
        float w = (k < Fdim) ? Wi[(long)k * 4096 + n] : Wh[(long)(k - Fdim) * 4096 + n];
        v[j] = (_Float16)w;
    }
    ((f16x8*)Wp)[d] = v;
}

__global__ void pack_misc_kernel(const float* __restrict__ bh, const float* __restrict__ h0,
                                 float* __restrict__ bias_p, _Float16* __restrict__ hbuf,
                                 unsigned int* __restrict__ flags)
{
    int t = blockIdx.x * blockDim.x + threadIdx.x;   // 0 .. 65535
    if (t < NWG) flags[t * FLAG_STRIDE] = 0u;        // re-armed every launch
    if (t < 4096) {
        int g = t >> 5, lc = t & 31;
        int gate = lc >> 3, c = lc & 7;
        bias_p[t] = bh[gate * Hdim + g * 8 + c];
    }
    {   // hbuf buffer 0 = h at t=0, compact layout [wg'][b][c]
        int wgp = t >> 9;
        int b   = (t >> 3) & 63;
        int c   = t & 7;
        hbuf[t] = (_Float16)h0[b * Hdim + wgp * 8 + c];
    }
}

__global__ __launch_bounds__(NTHR, 1)
void lstm_kernel(const float* __restrict__ x, const float* __restrict__ c0,
                 const f16x8* __restrict__ Wp8, const float* __restrict__ bias_p,
                 _Float16* __restrict__ hbuf, unsigned int* __restrict__ flags,
                 float* __restrict__ out)
{
    __shared__ f16x8 wlds[2 * NKB * 64];              // 96 KiB weight slice
    __shared__ float zlds[Bdim][33];                  // 8.25 KiB

    // XCD-grouped logical wg (keeps out-line sharers on one XCD)
    const int wg   = (blockIdx.x & 7) * 16 + (blockIdx.x >> 3);
    const int tid  = threadIdx.x;
    const int wave = tid >> 6;
    const int lane = tid & 63;
    const int kg = lane >> 4;
    const int lm = lane & 15;

    // ---- stage the WG's weight slice into LDS once ----
    {
        const f16x8* src = Wp8 + (size_t)wg * 2 * NKB * 64;
        for (int e = tid; e < 2 * NKB * 64; e += NTHR) wlds[e] = src[e];
    }

    const float bias0 = bias_p[wg * 32 + lm];
    const float bias1 = bias_p[wg * 32 + 16 + lm];

    // gate-phase ownership: wave 0, lane b owns all 8 h cols of batch row b
    float cc[8];
    if (wave == 0) {
#pragma unroll
        for (int c = 0; c < 8; ++c) cc[c] = c0[lane * Hdim + wg * 8 + c];
    }

    const int arow = wave * 16 + lm;                  // MFMA A-operand row (batch)
    const float* __restrict__ xrow = x + (size_t)arow * Tdim * Fdim + kg * 8;

    // per-lane h' read base (bytes): frag kb at +kb*4096
    const char* __restrict__ hrdbase =
        (const char*)hbuf + (size_t)kg * 1024 + (size_t)arow * 16;

    __syncthreads();                                  // wlds ready

    for (int t = 0; t < Tdim; ++t) {
        const int cur = t & 1;

        f32x4 acc0a = {bias0, bias0, bias0, bias0};
        f32x4 acc1a = {bias1, bias1, bias1, bias1};
        f32x4 acc0b = {0.f, 0.f, 0.f, 0.f};
        f32x4 acc1b = {0.f, 0.f, 0.f, 0.f};

        // ---- x part of K: load + cvt + MFMA per step (transient registers).
        //      Runs before the poll, overlapping other WGs' h(t) publish. ----
        {
            const float* xt = xrow + (size_t)t * Fdim;
#pragma unroll 8
            for (int kb = 0; kb < NXKB; ++kb) {
                const f32x4* ap = (const f32x4*)(xt + kb * 32);
                f32x4 lo = ap[0];
                f32x4 hi = ap[1];
                f16x8 a;
#pragma unroll
                for (int j = 0; j < 4; ++j) { a[j] = (_Float16)lo[j]; a[4 + j] = (_Float16)hi[j]; }
                f16x8 bf0 = wlds[kb * 64 + lane];
                f16x8 bf1 = wlds[NKB * 64 + kb * 64 + lane];
                if (kb & 1) { acc0b = MFMA(a, bf0, acc0b); acc1b = MFMA(a, bf1, acc1b); }
                else        { acc0a = MFMA(a, bf0, acc0a); acc1a = MFMA(a, bf1, acc1a); }
            }
        }

        // ---- wave 0 polls until all WGs published h(t); others wait at barrier ----
        if (t && wave == 0) {
            const unsigned int gen = (unsigned int)t;
            while (true) {
                unsigned int f0 = __hip_atomic_load(flags + (size_t)lane * FLAG_STRIDE,
                                                    __ATOMIC_RELAXED, __HIP_MEMORY_SCOPE_AGENT);
                unsigned int f1 = __hip_atomic_load(flags + (size_t)(64 + lane) * FLAG_STRIDE,
                                                    __ATOMIC_RELAXED, __HIP_MEMORY_SCOPE_AGENT);
                if (__all(f0 >= gen && f1 >= gen)) break;
                __builtin_amdgcn_s_sleep(2);
            }
        }
        __syncthreads();                              // (A) h(t) globally published

        // ---- h part of K: 32 batched device-coherent loads, ONE round trip ----
        f16x8 hfrag[NHKB];
        {
            const char* hq = hrdbase + (size_t)cur * (HBUF_HALF * 2);
#pragma unroll
            for (int kb = 0; kb < NHKB; ++kb)
                hfrag[kb] = uload16(hq + (size_t)kb * 4096);
        }
        asm volatile("s_waitcnt vmcnt(0)" ::: "memory");
        __builtin_amdgcn_sched_barrier(0);

#pragma unroll
        for (int kb = 0; kb < NHKB; ++kb) {
            f16x8 a   = hfrag[kb];
            f16x8 bf0 = wlds[(NXKB + kb) * 64 + lane];
            f16x8 bf1 = wlds[NKB * 64 + (NXKB + kb) * 64 + lane];
            if (kb & 1) { acc0b = MFMA(a, bf0, acc0b); acc1b = MFMA(a, bf1, acc1b); }
            else        { acc0a = MFMA(a, bf0, acc0a); acc1a = MFMA(a, bf1, acc1a); }
        }
        f32x4 z0 = acc0a + acc0b;
        f32x4 z1 = acc1a + acc1b;

        // D layout: row = (lane>>4)*4 + r, col = lane&15
        {
            int rbase = wave * 16 + kg * 4;
#pragma unroll
            for (int r = 0; r < 4; ++r) {
                zlds[rbase + r][lm]      = z0[r];
                zlds[rbase + r][16 + lm] = z1[r];
            }
        }
        __syncthreads();                              // (B) z ready

        if (wave == 0) {
            // ---- gates: lane b owns 8 cols (i=c, f=8+c, g=16+c, o=24+c) ----
            const int b = lane;
            float hv[8];
#pragma unroll
            for (int c = 0; c < 8; ++c) {
                float ig = sigmoidf_(zlds[b][c]);
                float fg = sigmoidf_(zlds[b][8 + c]);
                float gg = tanhf_(zlds[b][16 + c]);
                float og = sigmoidf_(zlds[b][24 + c]);
                cc[c] = fg * cc[c] + ig * gg;
                hv[c] = og * tanhf_(cc[c]);
            }
            // publish h(t+1): 16B contiguous per lane -> WG block fully covered
            union { _Float16 h[8]; unsigned long long u[2]; } pk;
#pragma unroll
            for (int c = 0; c < 8; ++c) pk.h[c] = (_Float16)hv[c];
            unsigned long long* hst = (unsigned long long*)
                (hbuf + (size_t)(cur ^ 1) * HBUF_HALF + (size_t)wg * 512 + (size_t)b * 8);
            __hip_atomic_store(hst,     pk.u[0], __ATOMIC_RELAXED, __HIP_MEMORY_SCOPE_AGENT);
            __hip_atomic_store(hst + 1, pk.u[1], __ATOMIC_RELAXED, __HIP_MEMORY_SCOPE_AGENT);
            asm volatile("s_waitcnt vmcnt(0)" ::: "memory");   // h' acked at MALL
            if (lane == 0)
                __hip_atomic_store(flags + (size_t)wg * FLAG_STRIDE, (unsigned int)(t + 1),
                                   __ATOMIC_RELAXED, __HIP_MEMORY_SCOPE_AGENT);
            // off-critical-path: out store (plain cached)
            float* op = out + ((size_t)b * Tdim + t) * Hdim + wg * 8;
            f32x4 o0 = {hv[0], hv[1], hv[2], hv[3]};
            f32x4 o1 = {hv[4], hv[5], hv[6], hv[7]};
            *(f32x4*)op       = o0;
            *(f32x4*)(op + 4) = o1;
        }
        // next iteration's barrier (A) orders: gates(t) done before zlds(t+1) writes
    }
}

extern "C" void kernel_launch(void* const* d_in, const int* in_sizes, int n_in,
                              void* d_out, int out_size, void* d_ws, size_t ws_size,
                              hipStream_t stream)
{
    const float* x  = (const float*)d_in[0];
    const float* c0 = (const float*)d_in[1];
    const float* h0 = (const float*)d_in[2];
    const float* Wi = (const float*)d_in[3];
    const float* Wh = (const float*)d_in[4];
    const float* bh = (const float*)d_in[5];
    float* out = (float*)d_out;

    char* ws = (char*)d_ws;
    _Float16*     Wp     = (_Float16*)(ws);
    float*        bias_p = (float*)(ws + BIAS_OFF);
    _Float16*     hbuf   = (_Float16*)(ws + HBUF_OFF);
    unsigned int* flags  = (unsigned int*)(ws + FLAG_OFF);

    hipLaunchKernelGGL(pack_w_kernel,    dim3(3072), dim3(256), 0, stream, Wi, Wh, Wp);
    hipLaunchKernelGGL(pack_misc_kernel, dim3(256),  dim3(256), 0, stream, bh, h0, bias_p, hbuf, flags);
    hipLaunchKernelGGL(lstm_kernel, dim3(NWG), dim3(NTHR), 0, stream,
                       x, c0, (const f16x8*)Wp, bias_p, hbuf, flags, out);
}

// Round 7
// 3583.629 us; speedup vs baseline: 2.8470x; 1.0853x over previous
//
#include <hip/hip_runtime.h>

#define Bdim 64
#define Tdim 512
#define Fdim 512
#define Hdim 1024
#define NKB  48          // K-blocks of 32: 16 for x (K=512) + 32 for h (K=1024)
#define NXKB 16
#define NHKB 32
#define NWG  128
#define NTHR 256

typedef __attribute__((ext_vector_type(8))) _Float16            f16x8;
typedef __attribute__((ext_vector_type(4))) float               f32x4;

#define MFMA(a, b, c) __builtin_amdgcn_mfma_f32_16x16x32_f16((a), (b), (c), 0, 0, 0)

// ---- workspace layout (bytes) ----
// Wp    : fp16 fragment-linear weights, 12.6 MB
// bias_p: fp32[4096]
// hbuf  : fp16[2][128 wg][64 b][8 c]  (2 x 128 KiB, compact per-WG blocks)
// flags : uint[NWG] padded to one 128B line each (stride 32 uints)
#define WP_ELEMS  (256*48*64*8)
#define BIAS_OFF  ((size_t)WP_ELEMS * 2)
#define HBUF_OFF  (BIAS_OFF + 4096 * 4)
#define HBUF_HALF 65536                              // halves per buffer (64*1024)
#define FLAG_OFF  (HBUF_OFF + (size_t)2 * HBUF_HALF * 2)
#define FLAG_STRIDE 32                               // uints (128 B) per flag

__device__ __forceinline__ float sigmoidf_(float v) {
    return 1.0f / (1.0f + __expf(-v));
}
__device__ __forceinline__ float tanhf_(float v) {
    return 1.0f - 2.0f / (1.0f + __expf(2.0f * v));
}

// Device-coherent (L1+L2 bypass) 16B load: data written via agent-scope
// write-through stores lives at the MALL; sc0 sc1 reads it fresh.
__device__ __forceinline__ f16x8 uload16(const void* p) {
    f16x8 r;
    asm volatile("global_load_dwordx4 %0, %1, off sc0 sc1"
                 : "=v"(r) : "v"(p) : "memory");
    return r;
}

// Counted vmcnt wait (completion is oldest-first) + scheduling fence (rule #18)
#define WAITV(N) do { asm volatile("s_waitcnt vmcnt(" #N ")" ::: "memory"); \
                      __builtin_amdgcn_sched_barrier(0); } while (0)

// Packed col Np = wg*32 + gate*8 + c  <->  orig col n = gate*1024 + wg*8 + c.
// Wp8[(tile*48 + kb)*64 + lane] = Wfull[kb*32 + (lane>>4)*8 + j][orig(tile*16 + (lane&15))]
__global__ void pack_w_kernel(const float* __restrict__ Wi, const float* __restrict__ Wh,
                              _Float16* __restrict__ Wp)
{
    int d = blockIdx.x * blockDim.x + threadIdx.x;   // 0 .. 786431
    int tn   = d / 3072;
    int r    = d % 3072;
    int kb   = r / 64;
    int lane = r % 64;
    int kg = lane >> 4, lm = lane & 15;
    int Np = tn * 16 + lm;
    int g    = Np >> 5;
    int lc   = Np & 31;
    int gate = lc >> 3, c = lc & 7;
    int n  = gate * Hdim + g * 8 + c;
    int k0 = kb * 32 + kg * 8;
    f16x8 v;
#pragma unroll
    for (int j = 0; j < 8; ++j) {
        int k = k0 + j;
        float w = (k < Fdim) ? Wi[(long)k * 4096 + n] : Wh[(long)(k - Fdim) * 4096 + n];
        v[j] = (_Float16)w;
    }
    ((f16x8*)Wp)[d] = v;
}

__global__ void pack_misc_kernel(const float* __restrict__ bh, const float* __restrict__ h0,
                                 float* __restrict__ bias_p, _Float16* __restrict__ hbuf,
                                 unsigned int* __restrict__ flags)
{
    int t = blockIdx.x * blockDim.x + threadIdx.x;   // 0 .. 65535
    if (t < NWG) flags[t * FLAG_STRIDE] = 0u;        // re-armed every launch
    if (t < 4096) {
        int g = t >> 5, lc = t & 31;
        int gate = lc >> 3, c = lc & 7;
        bias_p[t] = bh[gate * Hdim + g * 8 + c];
    }
    {   // hbuf buffer 0 = h at t=0, compact layout [wg'][b][c]
        int wgp = t >> 9;
        int b   = (t >> 3) & 63;
        int c   = t & 7;
        hbuf[t] = (_Float16)h0[b * Hdim + wgp * 8 + c];
    }
}

__global__ __launch_bounds__(NTHR, 1)
void lstm_kernel(const float* __restrict__ x, const float* __restrict__ c0,
                 const f16x8* __restrict__ Wp8, const float* __restrict__ bias_p,
                 _Float16* __restrict__ hbuf, unsigned int* __restrict__ flags,
                 float* __restrict__ out)
{
    __shared__ f16x8 wlds[2 * NKB * 64];              // 96 KiB weight slice
    __shared__ float zlds[Bdim][33];                  // 8.25 KiB (per-wave 16-row slices)

    // XCD-grouped logical wg (keeps out-line sharers on one XCD)
    const int wg   = (blockIdx.x & 7) * 16 + (blockIdx.x >> 3);
    const int tid  = threadIdx.x;
    const int wave = tid >> 6;
    const int lane = tid & 63;
    const int kg = lane >> 4;
    const int lm = lane & 15;

    // ---- stage the WG's weight slice into LDS once ----
    {
        const f16x8* src = Wp8 + (size_t)wg * 2 * NKB * 64;
        for (int e = tid; e < 2 * NKB * 64; e += NTHR) wlds[e] = src[e];
    }

    const float bias0 = bias_p[wg * 32 + lm];
    const float bias1 = bias_p[wg * 32 + 16 + lm];

    // gate-phase ownership (per-wave): wave w, lane l owns batch row
    // grow = 16w + (l>>2), cols gjl, gjl+1 where gjl = (l&3)*2.
    const int grow = wave * 16 + (lane >> 2);
    const int gjl  = (lane & 3) * 2;
    float cc0 = c0[grow * Hdim + wg * 8 + gjl];
    float cc1 = c0[grow * Hdim + wg * 8 + gjl + 1];

    const int arow = wave * 16 + lm;                  // MFMA A-operand row (batch)
    const float* __restrict__ xrow = x + (size_t)arow * Tdim * Fdim + kg * 8;

    // per-lane h' read base (bytes): frag kb at +kb*4096
    const char* __restrict__ hrdbase =
        (const char*)hbuf + (size_t)kg * 1024 + (size_t)arow * 16;

    __syncthreads();                                  // wlds ready

    for (int t = 0; t < Tdim; ++t) {
        const int cur = t & 1;

        f32x4 acc0a = {bias0, bias0, bias0, bias0};
        f32x4 acc1a = {bias1, bias1, bias1, bias1};
        f32x4 acc0b = {0.f, 0.f, 0.f, 0.f};
        f32x4 acc1b = {0.f, 0.f, 0.f, 0.f};

        // ---- x part of K: load + cvt + MFMA (transient regs);
        //      overlaps other WGs' h(t) publish latency ----
        {
            const float* xt = xrow + (size_t)t * Fdim;
#pragma unroll 8
            for (int kb = 0; kb < NXKB; ++kb) {
                const f32x4* ap = (const f32x4*)(xt + kb * 32);
                f32x4 lo = ap[0];
                f32x4 hi = ap[1];
                f16x8 a;
#pragma unroll
                for (int j = 0; j < 4; ++j) { a[j] = (_Float16)lo[j]; a[4 + j] = (_Float16)hi[j]; }
                f16x8 bf0 = wlds[kb * 64 + lane];
                f16x8 bf1 = wlds[NKB * 64 + kb * 64 + lane];
                if (kb & 1) { acc0b = MFMA(a, bf0, acc0b); acc1b = MFMA(a, bf1, acc1b); }
                else        { acc0a = MFMA(a, bf0, acc0a); acc1a = MFMA(a, bf1, acc1a); }
            }
        }

        // ---- wave 0 polls until all WGs published h(t); others wait at barrier ----
        if (t && wave == 0) {
            const unsigned int gen = (unsigned int)t;
            while (true) {
                unsigned int f0 = __hip_atomic_load(flags + (size_t)lane * FLAG_STRIDE,
                                                    __ATOMIC_RELAXED, __HIP_MEMORY_SCOPE_AGENT);
                unsigned int f1 = __hip_atomic_load(flags + (size_t)(64 + lane) * FLAG_STRIDE,
                                                    __ATOMIC_RELAXED, __HIP_MEMORY_SCOPE_AGENT);
                if (__all(f0 >= gen && f1 >= gen)) break;
                __builtin_amdgcn_s_sleep(2);
            }
        }
        __syncthreads();                              // (A) h(t) globally published

        // ---- h part of K: 2-group software pipeline, counted vmcnt (T4).
        //      Peak live = 16 fragments (64 VGPR) -> no spill. ----
        {
            const char* hq = hrdbase + (size_t)cur * (HBUF_HALF * 2);
            f16x8 hA[8], hB[8];
            WAITV(0);                                 // clean baseline (drains old out-store)

#define HLOAD(BASE, H)                                                  \
            _Pragma("unroll")                                           \
            for (int k = 0; k < 8; ++k)                                 \
                H[k] = uload16(hq + (size_t)((BASE) + k) * 4096);

#define HGROUP(BASE, H)                                                 \
            _Pragma("unroll")                                           \
            for (int k = 0; k < 8; ++k) {                               \
                int kb = (BASE) + k;                                    \
                f16x8 bf0 = wlds[(NXKB + kb) * 64 + lane];              \
                f16x8 bf1 = wlds[NKB * 64 + (NXKB + kb) * 64 + lane];   \
                if (kb & 1) { acc0b = MFMA(H[k], bf0, acc0b); acc1b = MFMA(H[k], bf1, acc1b); } \
                else        { acc0a = MFMA(H[k], bf0, acc0a); acc1a = MFMA(H[k], bf1, acc1a); } \
            }

            HLOAD(0,  hA);                            // g0 in flight
            HLOAD(8,  hB);                            // g1 in flight (16 outstanding)
            WAITV(8);                                 // g0 done
            HGROUP(0,  hA);
            HLOAD(16, hA);                            // g2 (WAR via dataflow)
            WAITV(8);                                 // g1 done
            HGROUP(8,  hB);
            HLOAD(24, hB);                            // g3
            WAITV(8);                                 // g2 done
            HGROUP(16, hA);
            WAITV(0);                                 // g3 done
            HGROUP(24, hB);
#undef HLOAD
#undef HGROUP
        }
        f32x4 z0 = acc0a + acc0b;
        f32x4 z1 = acc1a + acc1b;

        // D layout: row = (lane>>4)*4 + r, col = lane&15  (wave-private rows)
        {
            int rbase = wave * 16 + kg * 4;
#pragma unroll
            for (int r = 0; r < 4; ++r) {
                zlds[rbase + r][lm]      = z0[r];
                zlds[rbase + r][16 + lm] = z1[r];
            }
        }
        // wave-local transpose readback: no __syncthreads needed (rows are per-wave)
        asm volatile("s_waitcnt lgkmcnt(0)" ::: "memory");
        __builtin_amdgcn_sched_barrier(0);

        // ---- gates: all 256 lanes, 2 cols each (i=c, f=8+c, g=16+c, o=24+c) ----
        float hv0, hv1;
        {
            float i0 = sigmoidf_(zlds[grow][gjl]);
            float f0 = sigmoidf_(zlds[grow][8 + gjl]);
            float g0 = tanhf_(zlds[grow][16 + gjl]);
            float o0 = sigmoidf_(zlds[grow][24 + gjl]);
            cc0 = f0 * cc0 + i0 * g0;
            hv0 = o0 * tanhf_(cc0);

            float i1 = sigmoidf_(zlds[grow][gjl + 1]);
            float f1 = sigmoidf_(zlds[grow][8 + gjl + 1]);
            float g1 = tanhf_(zlds[grow][16 + gjl + 1]);
            float o1 = sigmoidf_(zlds[grow][24 + gjl + 1]);
            cc1 = f1 * cc1 + i1 * g1;
            hv1 = o1 * tanhf_(cc1);
        }

        // ---- publish h(t+1): pair-combine 4B->8B via shfl, even lanes store ----
        {
            union { _Float16 h[2]; unsigned int u; } pk;
            pk.h[0] = (_Float16)hv0; pk.h[1] = (_Float16)hv1;
            unsigned int nbu = __shfl(pk.u, lane ^ 1);
            if (!(lane & 1)) {
                unsigned long long v = (unsigned long long)pk.u
                                     | ((unsigned long long)nbu << 32);
                __hip_atomic_store((unsigned long long*)
                    (hbuf + (size_t)(cur ^ 1) * HBUF_HALF + (size_t)wg * 512
                          + (size_t)grow * 8 + gjl),
                    v, __ATOMIC_RELAXED, __HIP_MEMORY_SCOPE_AGENT);
            }
        }
        asm volatile("s_waitcnt vmcnt(0)" ::: "memory");   // h' acked at MALL
        __syncthreads();                              // (C) all waves' h' drained
        if (tid == 0)
            __hip_atomic_store(flags + (size_t)wg * FLAG_STRIDE, (unsigned int)(t + 1),
                               __ATOMIC_RELAXED, __HIP_MEMORY_SCOPE_AGENT);

        // off-critical-path: out store (plain cached, fire-and-forget)
        {
            float2 ov; ov.x = hv0; ov.y = hv1;
            *(float2*)(out + ((size_t)grow * Tdim + t) * Hdim + wg * 8 + gjl) = ov;
        }
    }
}

extern "C" void kernel_launch(void* const* d_in, const int* in_sizes, int n_in,
                              void* d_out, int out_size, void* d_ws, size_t ws_size,
                              hipStream_t stream)
{
    const float* x  = (const float*)d_in[0];
    const float* c0 = (const float*)d_in[1];
    const float* h0 = (const float*)d_in[2];
    const float* Wi = (const float*)d_in[3];
    const float* Wh = (const float*)d_in[4];
    const float* bh = (const float*)d_in[5];
    float* out = (float*)d_out;

    char* ws = (char*)d_ws;
    _Float16*     Wp     = (_Float16*)(ws);
    float*        bias_p = (float*)(ws + BIAS_OFF);
    _Float16*     hbuf   = (_Float16*)(ws + HBUF_OFF);
    unsigned int* flags  = (unsigned int*)(ws + FLAG_OFF);

    hipLaunchKernelGGL(pack_w_kernel,    dim3(3072), dim3(256), 0, stream, Wi, Wh, Wp);
    hipLaunchKernelGGL(pack_misc_kernel, dim3(256),  dim3(256), 0, stream, bh, h0, bias_p, hbuf, flags);
    hipLaunchKernelGGL(lstm_kernel, dim3(NWG), dim3(NTHR), 0, stream,
                       x, c0, (const f16x8*)Wp, bias_p, hbuf, flags, out);
}